// Round 9
// baseline (1250.741 us; speedup 1.0000x reference)
//
#include <hip/hip_runtime.h>

#define B_    1024
#define T_    256
#define LOCN  40001
#define E_    100
#define H_    100
#define NC    600   // [0,400): gates (i|f|g|o) preact, [400,500): t preact, [500,600): s preact

// Fast sigmoid: rcp(1 + exp2(-x*log2e)). v_exp_f32 + v_rcp_f32 are ~1 ulp.
__device__ __forceinline__ float fsig(float x) {
    const float e = __builtin_amdgcn_exp2f(x * -1.442695040888963f);
    return __builtin_amdgcn_rcpf(1.f + e);
}

// ---------------------------------------------------------------------------
// Kernel 1: P_loc[LOC][600] = emb_loc @ [W_ih | W_xt | W_xs] + [b | b_t | b_s]
// (round-0 proven version, PROWS=16)
// ---------------------------------------------------------------------------
constexpr int PROWS = 16;
constexpr int PPAD  = 20;   // pad 16->20 dwords: keeps 16B alignment for b128, breaks pow2 bank stride

__global__ __launch_bounds__(320) void proj_loc_kernel(
    const float* __restrict__ emb_loc,
    const float* __restrict__ W_ih,   // [100][400]
    const float* __restrict__ W_xt,   // [100][100]
    const float* __restrict__ W_xs,   // [100][100]
    const float* __restrict__ b,      // [400]
    const float* __restrict__ b_t,    // [100]
    const float* __restrict__ b_s,    // [100]
    float* __restrict__ P)            // [LOC][600]
{
    __shared__ __attribute__((aligned(16))) float aT[E_][PPAD];  // transposed tile
    const int tid  = threadIdx.x;
    const int row0 = blockIdx.x * PROWS;

    for (int i = tid; i < PROWS * E_; i += 320) {
        int r = i / E_, k = i - r * E_;
        int rr = row0 + r;
        float v = 0.f;
        if (rr < LOCN) v = emb_loc[rr * E_ + k];
        aT[k][r] = v;
    }
    __syncthreads();
    if (tid >= 300) return;

    for (int cc = 0; cc < 2; ++cc) {
        const int c = tid + cc * 300;
        const float* wp; int stride; float bias;
        if (c < 400)      { wp = W_ih + c;         stride = 400; bias = b[c]; }
        else if (c < 500) { wp = W_xt + (c - 400); stride = 100; bias = b_t[c - 400]; }
        else              { wp = W_xs + (c - 500); stride = 100; bias = b_s[c - 500]; }

        float acc[PROWS];
        #pragma unroll
        for (int r = 0; r < PROWS; ++r) acc[r] = bias;

        for (int k = 0; k < E_; ++k) {
            float w = wp[(size_t)k * stride];
            #pragma unroll
            for (int r = 0; r < PROWS; ++r) acc[r] += aT[k][r] * w;
        }
        #pragma unroll
        for (int r = 0; r < PROWS; ++r) {
            int rr = row0 + r;
            if (rr < LOCN) P[(size_t)rr * NC + c] = acc[r];
        }
    }
}

// ---------------------------------------------------------------------------
// Kernel 2: P_t[92][100] = emb_t @ W_tt ; P_s[92][100] = emb_s @ W_ss
// ---------------------------------------------------------------------------
__global__ void proj_ts_kernel(
    const float* __restrict__ emb_t, const float* __restrict__ emb_s,
    const float* __restrict__ W_tt,  const float* __restrict__ W_ss,
    float* __restrict__ P_t, float* __restrict__ P_s)
{
    int idx = blockIdx.x * 256 + threadIdx.x;
    if (idx >= 2 * 92 * H_) return;
    int which = idx / (92 * H_);
    int rem   = idx - which * (92 * H_);
    int r = rem / H_, c = rem - r * H_;
    const float* e = which ? emb_s : emb_t;
    const float* W = which ? W_ss : W_tt;
    float acc = 0.f;
    #pragma unroll
    for (int k = 0; k < 12; ++k) acc += e[r * 12 + k] * W[k * H_ + c];
    (which ? P_s : P_t)[rem] = acc;
}

// ---------------------------------------------------------------------------
// Kernel 3: recurrence. Round-7 frame (RB=4, NT=704, grid=256, 621 us) +
// one-step-ahead register prefetch of ALL scattered loads:
//  - gate gather gacc(t+1) issued before the FMA block (hidden under 400 FMAs)
//  - ts inputs (up/low/pql/pqu/gp)(t+1) issued after the ts compute (hidden
//    under barrier1 + epilogue + barrier2 + next section)
//  - loc lookahead extended to t+2 via loc_lds double buffer
//  - raw barriers (s_waitcnt lgkmcnt(0); s_barrier): prefetch global loads
//    stay IN FLIGHT across barriers (__syncthreads would drain vmcnt=0)
// Rationale: R7/R8 showed fixed 436 VALU-us at 65-70% issue; occupancy is
// register-capped at 1 block/CU (w[100] in AGPRs), so the ~30% stall must be
// removed by latency-hiding, not TLP. The serial int->Pq->gp chain in the ts
// section was the exposed critical path.
// ---------------------------------------------------------------------------
constexpr int RB = 4;
constexpr int NT = 704;

__global__ __launch_bounds__(NT, 3) void lstm_rec_kernel(
    const int* __restrict__ traj,
    const int* __restrict__ traj_len_p,
    const int* __restrict__ tu,      const int* __restrict__ tl,
    const int* __restrict__ tu_slot, const int* __restrict__ tl_slot,
    const int* __restrict__ su,      const int* __restrict__ sl,
    const int* __restrict__ su_slot, const int* __restrict__ sl_slot,
    const float* __restrict__ P,     // [LOC][600]
    const float* __restrict__ P_t,   // [92][100]
    const float* __restrict__ P_s,   // [92][100]
    const float* __restrict__ W_hh,  // [100][400]
    float* __restrict__ out)         // [B][100]
{
    __shared__ __attribute__((aligned(16))) float h_lds[RB][H_];
    __shared__ float gates_lds[RB][400];
    __shared__ float tg_lds[RB][H_];
    __shared__ float sg_lds[RB][H_];
    __shared__ int   loc_lds[2][RB];

    const int tid = threadIdx.x;
    const int b0  = blockIdx.x * RB;
    int steps = traj_len_p[0] + 1;
    if (steps > T_) steps = T_;

    // W_hh column -> registers (persist across all 256 steps)
    float w[H_];
    if (tid < 400) {
        #pragma unroll
        for (int k = 0; k < H_; ++k) w[k] = W_hh[k * 400 + tid];
        ((float*)h_lds)[tid] = 0.f;
    }

    // ---- role constants ----
    const bool isTS = (tid >= 448 && tid < 648);
    const int  ch   = tid - 448;          // 0..199 when isTS
    const bool is_t = ch < 100;
    const int  hx   = is_t ? ch : ch - 100;
    const int* up_a = is_t ? tu_slot : su_slot;
    const int* lo_a = is_t ? tl_slot : sl_slot;
    const int* ui_a = is_t ? tu : su;
    const int* li_a = is_t ? tl : sl;
    const float* Pq = is_t ? P_t : P_s;
    const int  gcol = (is_t ? 400 : 500) + hx;
    float* dst      = is_t ? &tg_lds[0][0] : &sg_lds[0][0];

    const int er = tid / 100;        // epilogue row   (valid for tid<400)
    const int eh = tid - er * 100;   // epilogue h-idx

    // ---- prologue: prefetch state for step 0 ----
    float gacc_cur[RB];
    float ts_up[RB], ts_lo[RB], ts_gp[RB], ts_pql[RB], ts_pqu[RB];

    if (tid < 400) {
        #pragma unroll
        for (int r = 0; r < RB; ++r) {
            const int loc0 = __builtin_amdgcn_readfirstlane(traj[(b0 + r) * T_]);
            gacc_cur[r] = P[(size_t)loc0 * NC + tid];
        }
    }
    if (isTS) {
        #pragma unroll
        for (int r = 0; r < RB; ++r) {
            const int off0 = __builtin_amdgcn_readfirstlane((b0 + r) * T_);
            const int loc0 = __builtin_amdgcn_readfirstlane(traj[off0]);
            ts_up[r] = (float)up_a[off0];
            ts_lo[r] = (float)lo_a[off0];
            const int ui = ui_a[off0], li = li_a[off0];
            ts_gp[r]  = P[(size_t)loc0 * NC + gcol];
            ts_pql[r] = Pq[li * H_ + hx];
            ts_pqu[r] = Pq[ui * H_ + hx];
        }
    }
    if (tid < RB) {
        const int t1 = (steps > 1) ? 1 : 0;
        loc_lds[1][tid] = traj[(b0 + tid) * T_ + t1];   // loc[1] -> slot 1
    }
    float c_reg = 0.f, hval = 0.f;
    __syncthreads();

    for (int t = 0; t < steps; ++t) {
        const int buf = t & 1;

        if (tid >= 700) {                       // prefetch loc[t+2] into slot buf
            const int r  = tid - 700;
            const int t2 = (t + 2 < steps) ? t + 2 : steps - 1;
            loc_lds[buf][r] = traj[(b0 + r) * T_ + t2];
        }

        if (tid < 400) {                        // ---- gates ----
            const int n = tid;
            // issue next-step gather first (hidden under the FMA block)
            float gacc_nxt[RB];
            #pragma unroll
            for (int r = 0; r < RB; ++r) {
                const int locN = __builtin_amdgcn_readfirstlane(loc_lds[buf ^ 1][r]);
                gacc_nxt[r] = P[(size_t)locN * NC + n];
            }
            // h @ W_hh
            float acc[RB] = {0.f, 0.f, 0.f, 0.f};
            #pragma unroll
            for (int k4 = 0; k4 < H_ / 4; ++k4) {
                #pragma unroll
                for (int r = 0; r < RB; ++r) {
                    float4 hv = *(const float4*)(&h_lds[r][k4 * 4]);
                    acc[r] += hv.x * w[k4 * 4 + 0];
                    acc[r] += hv.y * w[k4 * 4 + 1];
                    acc[r] += hv.z * w[k4 * 4 + 2];
                    acc[r] += hv.w * w[k4 * 4 + 3];
                }
            }
            const bool isg = (n >= 200 && n < 300);   // g-gate -> tanh via 2*sig(2x)-1
            #pragma unroll
            for (int r = 0; r < RB; ++r) {
                float v  = acc[r] + gacc_cur[r];
                float xx = isg ? 2.f * v : v;
                float s  = fsig(xx);
                gates_lds[r][n] = isg ? (2.f * s - 1.f) : s;
            }
            #pragma unroll
            for (int r = 0; r < RB; ++r) gacc_cur[r] = gacc_nxt[r];
        }

        if (isTS) {                             // ---- t/s gates ----
            // compute current step entirely from prefetched registers
            #pragma unroll
            for (int r = 0; r < RB; ++r) {
                const float inv = __builtin_amdgcn_rcpf(fmaxf(ts_up[r] + ts_lo[r], 1.f));
                const float iv  = (ts_up[r] * ts_pql[r] + ts_lo[r] * ts_pqu[r]) * inv;
                dst[r * H_ + hx] = fsig(ts_gp[r] + iv);
            }
            // prefetch next step's inputs (in-place; latency spans 2 barriers)
            const int tn = (t + 1 < steps) ? t + 1 : steps - 1;
            #pragma unroll
            for (int r = 0; r < RB; ++r) {
                const int offN = __builtin_amdgcn_readfirstlane((b0 + r) * T_ + tn);
                const int locN = __builtin_amdgcn_readfirstlane(loc_lds[buf ^ 1][r]);
                ts_up[r] = (float)up_a[offN];
                ts_lo[r] = (float)lo_a[offN];
                const int ui = ui_a[offN], li = li_a[offN];
                ts_gp[r]  = P[(size_t)locN * NC + gcol];
                ts_pql[r] = Pq[li * H_ + hx];
                ts_pqu[r] = Pq[ui * H_ + hx];
            }
        }
        // barrier 1: drain LDS only; keep global prefetches in flight
        asm volatile("s_waitcnt lgkmcnt(0)\n\ts_barrier" ::: "memory");

        if (tid < 400) {                        // ---- epilogue: c,h update ----
            float i_g = gates_lds[er][eh];
            float f_g = gates_lds[er][100 + eh];
            float g_g = gates_lds[er][200 + eh];
            float o_g = gates_lds[er][300 + eh];
            float tsg = tg_lds[er][eh] * sg_lds[er][eh];
            c_reg = f_g * c_reg + i_g * tsg * g_g;
            hval  = o_g * (2.f * fsig(2.f * c_reg) - 1.f);   // tanh = 2*sig(2x)-1
            h_lds[er][eh] = hval;
        }
        // barrier 2
        asm volatile("s_waitcnt lgkmcnt(0)\n\ts_barrier" ::: "memory");
    }

    if (tid < 400) out[b0 * H_ + tid] = hval;
}

// ---------------------------------------------------------------------------
extern "C" void kernel_launch(void* const* d_in, const int* in_sizes, int n_in,
                              void* d_out, int out_size, void* d_ws, size_t ws_size,
                              hipStream_t stream) {
    const int*   traj     = (const int*)  d_in[0];
    // d_in[1] = lennew (unused by the reference)
    const int*   traj_len = (const int*)  d_in[2];
    const int*   tu       = (const int*)  d_in[3];
    const int*   tl       = (const int*)  d_in[4];
    const int*   tu_slot  = (const int*)  d_in[5];
    const int*   tl_slot  = (const int*)  d_in[6];
    const int*   su       = (const int*)  d_in[7];
    const int*   sl       = (const int*)  d_in[8];
    const int*   su_slot  = (const int*)  d_in[9];
    const int*   sl_slot  = (const int*)  d_in[10];
    const float* emb_loc  = (const float*)d_in[11];
    const float* emb_t    = (const float*)d_in[12];
    const float* emb_s    = (const float*)d_in[13];
    const float* W_ih     = (const float*)d_in[14];
    const float* W_hh     = (const float*)d_in[15];
    const float* b        = (const float*)d_in[16];
    const float* W_xt     = (const float*)d_in[17];
    const float* W_tt     = (const float*)d_in[18];
    const float* b_t      = (const float*)d_in[19];
    const float* W_xs     = (const float*)d_in[20];
    const float* W_ss     = (const float*)d_in[21];
    const float* b_s      = (const float*)d_in[22];

    float* P   = (float*)d_ws;              // 40001*600 = 24,000,600 floats (96.0 MB)
    float* P_t = P + (size_t)LOCN * NC;     // 9200 floats
    float* P_s = P_t + 92 * H_;             // 9200 floats

    proj_loc_kernel<<<(LOCN + PROWS - 1) / PROWS, 320, 0, stream>>>(
        emb_loc, W_ih, W_xt, W_xs, b, b_t, b_s, P);
    proj_ts_kernel<<<(2 * 92 * H_ + 255) / 256, 256, 0, stream>>>(
        emb_t, emb_s, W_tt, W_ss, P_t, P_s);
    lstm_rec_kernel<<<B_ / RB, NT, 0, stream>>>(
        traj, traj_len, tu, tl, tu_slot, tl_slot, su, sl, su_slot, sl_slot,
        P, P_t, P_s, W_hh, (float*)d_out);
}

// Round 10
// 786.167 us; speedup vs baseline: 1.5909x; 1.5909x over previous
//
#include <hip/hip_runtime.h>

#define B_    1024
#define T_    256
#define LOCN  40001
#define E_    100
#define H_    100
#define NC    600   // [0,400): gates (i|f|g|o) preact, [400,500): t preact, [500,600): s preact

typedef float f32x2 __attribute__((ext_vector_type(2)));

// Fast sigmoid: rcp(1 + exp2(-x*log2e)). v_exp_f32 + v_rcp_f32 are ~1 ulp.
__device__ __forceinline__ float fsig(float x) {
    const float e = __builtin_amdgcn_exp2f(x * -1.442695040888963f);
    return __builtin_amdgcn_rcpf(1.f + e);
}

// ---------------------------------------------------------------------------
// Kernel 1: P_loc[LOC][600] = emb_loc @ [W_ih | W_xt | W_xs] + [b | b_t | b_s]
// (round-0 proven version, PROWS=16)
// ---------------------------------------------------------------------------
constexpr int PROWS = 16;
constexpr int PPAD  = 20;   // pad 16->20 dwords: keeps 16B alignment for b128, breaks pow2 bank stride

__global__ __launch_bounds__(320) void proj_loc_kernel(
    const float* __restrict__ emb_loc,
    const float* __restrict__ W_ih,   // [100][400]
    const float* __restrict__ W_xt,   // [100][100]
    const float* __restrict__ W_xs,   // [100][100]
    const float* __restrict__ b,      // [400]
    const float* __restrict__ b_t,    // [100]
    const float* __restrict__ b_s,    // [100]
    float* __restrict__ P)            // [LOC][600]
{
    __shared__ __attribute__((aligned(16))) float aT[E_][PPAD];  // transposed tile
    const int tid  = threadIdx.x;
    const int row0 = blockIdx.x * PROWS;

    for (int i = tid; i < PROWS * E_; i += 320) {
        int r = i / E_, k = i - r * E_;
        int rr = row0 + r;
        float v = 0.f;
        if (rr < LOCN) v = emb_loc[rr * E_ + k];
        aT[k][r] = v;
    }
    __syncthreads();
    if (tid >= 300) return;

    for (int cc = 0; cc < 2; ++cc) {
        const int c = tid + cc * 300;
        const float* wp; int stride; float bias;
        if (c < 400)      { wp = W_ih + c;         stride = 400; bias = b[c]; }
        else if (c < 500) { wp = W_xt + (c - 400); stride = 100; bias = b_t[c - 400]; }
        else              { wp = W_xs + (c - 500); stride = 100; bias = b_s[c - 500]; }

        float acc[PROWS];
        #pragma unroll
        for (int r = 0; r < PROWS; ++r) acc[r] = bias;

        for (int k = 0; k < E_; ++k) {
            float w = wp[(size_t)k * stride];
            #pragma unroll
            for (int r = 0; r < PROWS; ++r) acc[r] += aT[k][r] * w;
        }
        #pragma unroll
        for (int r = 0; r < PROWS; ++r) {
            int rr = row0 + r;
            if (rr < LOCN) P[(size_t)rr * NC + c] = acc[r];
        }
    }
}

// ---------------------------------------------------------------------------
// Kernel 2: P_t[92][100] = emb_t @ W_tt ; P_s[92][100] = emb_s @ W_ss
// ---------------------------------------------------------------------------
__global__ void proj_ts_kernel(
    const float* __restrict__ emb_t, const float* __restrict__ emb_s,
    const float* __restrict__ W_tt,  const float* __restrict__ W_ss,
    float* __restrict__ P_t, float* __restrict__ P_s)
{
    int idx = blockIdx.x * 256 + threadIdx.x;
    if (idx >= 2 * 92 * H_) return;
    int which = idx / (92 * H_);
    int rem   = idx - which * (92 * H_);
    int r = rem / H_, c = rem - r * H_;
    const float* e = which ? emb_s : emb_t;
    const float* W = which ? W_ss : W_tt;
    float acc = 0.f;
    #pragma unroll
    for (int k = 0; k < 12; ++k) acc += e[r * 12 + k] * W[k * H_ + c];
    (which ? P_s : P_t)[rem] = acc;
}

// ---------------------------------------------------------------------------
// Kernel 3: the recurrence. EXACT round-7 frame (RB=4, NT=704, grid=256,
// two __syncthreads per step, compiler-scheduled loads -- 621 us proven;
// every hand-pipelining attempt regressed). ONE change: the h @ W_hh inner
// loop is rewritten in f32x2 so the backend emits v_pk_fma_f32 (CDNA packed
// FP32, 2 MACs/instr at full rate) -- halves the dominant VALU-issue term
// (400 v_fmac/thread/step -> 200 v_pk_fma). h still read as float4 b128
// (no extra LDS traffic); pairs split in-register. Downside ~0: if the
// backend scalarizes we are back to the round-7 stream.
// ---------------------------------------------------------------------------
constexpr int RB = 4;
constexpr int NT = 704;

__global__ __launch_bounds__(NT, 3) void lstm_rec_kernel(
    const int* __restrict__ traj,
    const int* __restrict__ traj_len_p,
    const int* __restrict__ tu,      const int* __restrict__ tl,
    const int* __restrict__ tu_slot, const int* __restrict__ tl_slot,
    const int* __restrict__ su,      const int* __restrict__ sl,
    const int* __restrict__ su_slot, const int* __restrict__ sl_slot,
    const float* __restrict__ P,     // [LOC][600]
    const float* __restrict__ P_t,   // [92][100]
    const float* __restrict__ P_s,   // [92][100]
    const float* __restrict__ W_hh,  // [100][400]
    float* __restrict__ out)         // [B][100]
{
    __shared__ __attribute__((aligned(16))) float h_lds[RB][H_];
    __shared__ float gates_lds[RB][400];
    __shared__ float tg_lds[RB][H_];
    __shared__ float sg_lds[RB][H_];
    __shared__ int   loc_lds[2][RB];

    const int tid = threadIdx.x;
    const int b0  = blockIdx.x * RB;
    int steps = traj_len_p[0] + 1;
    if (steps > T_) steps = T_;

    // W_hh column -> register pairs (persist across all 256 steps)
    f32x2 w2[50];
    if (tid < 400) {
        #pragma unroll
        for (int j = 0; j < 50; ++j) {
            w2[j].x = W_hh[(2 * j)     * 400 + tid];
            w2[j].y = W_hh[(2 * j + 1) * 400 + tid];
        }
        ((float*)h_lds)[tid] = 0.f;
    }
    if (tid < RB) loc_lds[0][tid] = traj[(b0 + tid) * T_];

    const int er = tid / 100;        // epilogue row   (valid for tid<400)
    const int eh = tid - er * 100;   // epilogue h-idx
    float c_reg = 0.f, hval = 0.f;
    __syncthreads();

    for (int t = 0; t < steps; ++t) {
        const int buf = t & 1;

        if (tid >= 700) {                       // prefetch next step's locations
            int r = tid - 700;
            if (t + 1 < steps) loc_lds[buf ^ 1][r] = traj[(b0 + r) * T_ + t + 1];
        }

        if (tid < 400) {                        // ---- gates: gather + h @ W_hh ----
            const int n = tid;
            float gacc[RB];
            #pragma unroll
            for (int r = 0; r < RB; ++r) {
                const int loc = __builtin_amdgcn_readfirstlane(loc_lds[buf][r]);
                const float* __restrict__ Prow = P + (size_t)loc * NC;  // SGPR base
                gacc[r] = Prow[n];
            }

            f32x2 acc2[RB];
            #pragma unroll
            for (int r = 0; r < RB; ++r) acc2[r] = (f32x2){0.f, 0.f};
            #pragma unroll
            for (int k4 = 0; k4 < H_ / 4; ++k4) {
                #pragma unroll
                for (int r = 0; r < RB; ++r) {
                    const float4 hv = *(const float4*)(&h_lds[r][k4 * 4]);
                    const f32x2 hlo = {hv.x, hv.y};
                    const f32x2 hhi = {hv.z, hv.w};
                    acc2[r] = hlo * w2[2 * k4]     + acc2[r];   // v_pk_fma_f32
                    acc2[r] = hhi * w2[2 * k4 + 1] + acc2[r];   // v_pk_fma_f32
                }
            }
            const bool isg = (n >= 200 && n < 300);   // g-gate -> tanh via 2*sig(2x)-1
            #pragma unroll
            for (int r = 0; r < RB; ++r) {
                float v  = (acc2[r].x + acc2[r].y) + gacc[r];
                float xx = isg ? 2.f * v : v;
                float s  = fsig(xx);
                gates_lds[r][n] = isg ? (2.f * s - 1.f) : s;
            }
        }

        if (tid >= 448 && tid < 648) {          // ---- t/s gates (h-independent) ----
            const int  ch   = tid - 448;        // 0..199
            const bool is_t = ch < 100;
            const int  hx   = is_t ? ch : ch - 100;
            const int* up_a = is_t ? tu_slot : su_slot;
            const int* lo_a = is_t ? tl_slot : sl_slot;
            const int* ui_a = is_t ? tu : su;
            const int* li_a = is_t ? tl : sl;
            const float* Pq = is_t ? P_t : P_s;
            float* dst      = is_t ? &tg_lds[0][0] : &sg_lds[0][0];
            #pragma unroll
            for (int r = 0; r < RB; ++r) {
                const int off = __builtin_amdgcn_readfirstlane((b0 + r) * T_ + t);
                const int loc = __builtin_amdgcn_readfirstlane(loc_lds[buf][r]);
                const float* __restrict__ Prow = P + (size_t)loc * NC;  // SGPR base
                float gp  = Prow[400 + ch];
                float up  = (float)up_a[off];
                float low = (float)lo_a[off];
                int   ui  = ui_a[off], li = li_a[off];
                // interp @ W = (up*Pq[low_idx] + low*Pq[up_idx]) * rcp(max(up+low,1))
                const float inv = __builtin_amdgcn_rcpf(fmaxf(up + low, 1.f));
                float iv  = (up * Pq[li * H_ + hx] + low * Pq[ui * H_ + hx]) * inv;
                float pre = gp + iv;
                dst[r * H_ + hx] = fsig(pre);
            }
        }
        __syncthreads();

        if (tid < 400) {                        // ---- epilogue: c,h update ----
            float i_g = gates_lds[er][eh];
            float f_g = gates_lds[er][100 + eh];
            float g_g = gates_lds[er][200 + eh];
            float o_g = gates_lds[er][300 + eh];
            float tsg = tg_lds[er][eh] * sg_lds[er][eh];
            c_reg = f_g * c_reg + i_g * tsg * g_g;
            hval  = o_g * (2.f * fsig(2.f * c_reg) - 1.f);   // tanh = 2*sig(2x)-1
            h_lds[er][eh] = hval;
        }
        __syncthreads();
    }

    if (tid < 400) out[b0 * H_ + tid] = hval;
}

// ---------------------------------------------------------------------------
extern "C" void kernel_launch(void* const* d_in, const int* in_sizes, int n_in,
                              void* d_out, int out_size, void* d_ws, size_t ws_size,
                              hipStream_t stream) {
    const int*   traj     = (const int*)  d_in[0];
    // d_in[1] = lennew (unused by the reference)
    const int*   traj_len = (const int*)  d_in[2];
    const int*   tu       = (const int*)  d_in[3];
    const int*   tl       = (const int*)  d_in[4];
    const int*   tu_slot  = (const int*)  d_in[5];
    const int*   tl_slot  = (const int*)  d_in[6];
    const int*   su       = (const int*)  d_in[7];
    const int*   sl       = (const int*)  d_in[8];
    const int*   su_slot  = (const int*)  d_in[9];
    const int*   sl_slot  = (const int*)  d_in[10];
    const float* emb_loc  = (const float*)d_in[11];
    const float* emb_t    = (const float*)d_in[12];
    const float* emb_s    = (const float*)d_in[13];
    const float* W_ih     = (const float*)d_in[14];
    const float* W_hh     = (const float*)d_in[15];
    const float* b        = (const float*)d_in[16];
    const float* W_xt     = (const float*)d_in[17];
    const float* W_tt     = (const float*)d_in[18];
    const float* b_t      = (const float*)d_in[19];
    const float* W_xs     = (const float*)d_in[20];
    const float* W_ss     = (const float*)d_in[21];
    const float* b_s      = (const float*)d_in[22];

    float* P   = (float*)d_ws;              // 40001*600 = 24,000,600 floats (96.0 MB)
    float* P_t = P + (size_t)LOCN * NC;     // 9200 floats
    float* P_s = P_t + 92 * H_;             // 9200 floats

    proj_loc_kernel<<<(LOCN + PROWS - 1) / PROWS, 320, 0, stream>>>(
        emb_loc, W_ih, W_xt, W_xs, b, b_t, b_s, P);
    proj_ts_kernel<<<(2 * 92 * H_ + 255) / 256, 256, 0, stream>>>(
        emb_t, emb_s, W_tt, W_ss, P_t, P_s);
    lstm_rec_kernel<<<B_ / RB, NT, 0, stream>>>(
        traj, traj_len, tu, tl, tu_slot, tl_slot, su, sl, su_slot, sl_slot,
        P, P_t, P_s, W_hh, (float*)d_out);
}